// Round 5
// baseline (95.249 us; speedup 1.0000x reference)
//
#include <hip/hip_runtime.h>
#include <hip/hip_bf16.h>
#include <stdint.h>

typedef __bf16 bf16_t;
typedef __bf16 bf16x8 __attribute__((ext_vector_type(8)));
typedef float  f32x4  __attribute__((ext_vector_type(4)));
typedef float  f32x16 __attribute__((ext_vector_type(16)));
typedef unsigned int uint;

#define MFMA16(a,b,c) __builtin_amdgcn_mfma_f32_16x16x32_bf16((a),(b),(c),0,0,0)
#define MFMA32(a,b,c) __builtin_amdgcn_mfma_f32_32x32x16_bf16((a),(b),(c),0,0,0)

constexpr int NB = 16;
constexpr int LQ = 8192;
constexpr int LK = 128;
constexpr int H  = 128;

// log2(e) / sqrt(H): fold softmax scale + exp2 conversion into one multiply
constexpr float C1 = 1.4426950408889634f / 11.313708498984761f;

constexpr size_t WS_FLAG = 0;
constexpr size_t WS_W2T  = 1024;    // (wq^T wk), 128x128 bf16 row-major

// XOR swizzle for [*][128] bf16 LDS tiles (row stride 256 B)
__device__ __forceinline__ unsigned swz(unsigned row, unsigned byte) {
  return row * 256u + (byte ^ ((row & 15u) << 4));
}

__device__ __forceinline__ bf16x8 cvt_frag(const float* p) {
  f32x4 u0 = *(const f32x4*)p;
  f32x4 u1 = *(const f32x4*)(p + 4);
  bf16x8 v;
  #pragma unroll
  for (int e = 0; e < 4; ++e) { v[e] = (bf16_t)u0[e]; v[e + 4] = (bf16_t)u1[e]; }
  return v;
}

__device__ __forceinline__ f32x16 zero16() {
  f32x16 z;
  #pragma unroll
  for (int i = 0; i < 16; ++i) z[i] = 0.f;
  return z;
}

// v_cvt_pk_bf16_f32: lo = bf16(a), hi = bf16(b)
__device__ __forceinline__ uint pkbf(float a, float b) {
  uint d;
  asm("v_cvt_pk_bf16_f32 %0, %1, %2" : "=v"(d) : "v"(a), "v"(b));
  return d;
}

// ---------------------------------------------------------------------------
// prep0 (1 block): W2T = wq^T @ wk (bf16 to ws) + mask dtype probe
// ---------------------------------------------------------------------------
__global__ __launch_bounds__(512) void prep0_kernel(
    const float* __restrict__ wq, const float* __restrict__ wk,
    const unsigned* __restrict__ x3w, uint8_t* __restrict__ ws)
{
  __shared__ uint8_t sT[65536];   // wqT | wkT, each [128][128] bf16 swizzled
  const int tid = threadIdx.x;
  const int row = tid >> 2, c0 = (tid & 3) * 32;

  #pragma unroll
  for (int which = 0; which < 2; ++which) {
    const float* W = which ? wk : wq;
    uint8_t* dst = sT + which * 32768;
    const float* s = W + row * H + c0;
    #pragma unroll
    for (int j = 0; j < 32; ++j)
      *(bf16_t*)(dst + swz(c0 + j, row * 2)) = (bf16_t)s[j];
  }

  __shared__ int sF32, sBig;
  if (tid == 0) { sF32 = 0; sBig = 0; }
  __syncthreads();
  {
    int f = 0, g = 0;
    #pragma unroll
    for (int j = 0; j < 4; ++j) {
      unsigned v = x3w[tid * 4 + j];
      if (v == 0x3f800000u) f = 1;
      else if (v > 1u) g = 1;
    }
    if (f) sF32 = 1;
    if (g) sBig = 1;
  }
  __syncthreads();
  if (tid == 0) *(int*)(ws + WS_FLAG) = (sF32 == 0 && sBig == 1) ? 1 : 0;

  // W2T[i][j] = sum_k wq[k][i] wk[k][j]
  const int lane = tid & 63, w = tid >> 6, lo = lane & 15, hi = lane >> 4;
  bf16x8 a[4];
  #pragma unroll
  for (int kk = 0; kk < 4; ++kk)
    a[kk] = *(const bf16x8*)(sT + swz(16 * w + lo, kk * 64 + hi * 16));
  bf16_t* W2T = (bf16_t*)(ws + WS_W2T);
  #pragma unroll
  for (int t = 0; t < 8; ++t) {
    f32x4 c = {0.f, 0.f, 0.f, 0.f};
    #pragma unroll
    for (int kk = 0; kk < 4; ++kk)
      c = MFMA16(a[kk], *(const bf16x8*)(sT + 32768 + swz(16 * t + lo, kk * 64 + hi * 16)), c);
    #pragma unroll
    for (int r = 0; r < 4; ++r)
      W2T[(16 * w + hi * 4 + r) * H + 16 * t + lo] = (bf16_t)c[r];
  }
}

// ---------------------------------------------------------------------------
// Main fused kernel, 32x32x16 MFMA throughout.
// Block = (batch b, 256-q chunk), 8 waves, grid 512, LDS 64 KB -> 2 blk/CU.
//   waves 0-3 build M = x2(wq^T wk)^T -> sM; waves 4-7 build V = x2 wv^T -> sV
//   per wave (32 q): S^T[j][q] = MFMA32(A=M, B=x1^T)  (q = lane&31 -> lane-local!)
//   p = exp2(S*C1) masked in C-regs (no max shift; validated r4)
//   P^T B-frags built IN-REGISTER: cvt_pk_bf16 pairs + v_permlane32_swap
//   dsum via ones-A MFMA on pb; O[i][q] = MFMA32(A=V, B=P^T)
//   stores: per instr 64 lanes = 2 rows x 32 consecutive q x 4B = full 128B lines
// ---------------------------------------------------------------------------
__global__ __launch_bounds__(512, 4) void attn_kernel(
    const float* __restrict__ x1, const float* __restrict__ x2,
    const float* __restrict__ wv, const void* __restrict__ x3,
    const uint8_t* __restrict__ ws, float* __restrict__ out)
{
  __shared__ uint8_t sm[65536];
  uint8_t* sM = sm;            // M [128 j][128 c] bf16 swizzled
  uint8_t* sV = sm + 32768;    // V [128 i][128 j] bf16 swizzled

  const int tid = threadIdx.x, blk = blockIdx.x;
  const int b = blk >> 5, qc = (blk & 31) * 256;
  const int l = tid & 63, w = tid >> 6;
  const int q31 = l & 31, hi2 = l >> 5;
  const int byteMode = *(const int*)(ws + WS_FLAG);

  const int q0w = qc + w * 32;
  const size_t qrow = (size_t)b * LQ + q0w + q31;   // this lane's q row

  // ---- x1 B-frags: B[k][q]: n=q31, k = kt*16 + 8*hi2 + e ----
  bf16x8 xb[8];
  {
    const float* xr = x1 + qrow * H;
    #pragma unroll
    for (int kt = 0; kt < 8; ++kt)
      xb[kt] = cvt_frag(xr + kt * 16 + 8 * hi2);
  }

  // ---- mask prefetch (byte mode): reg r of j-tile jt needs byte
  //      j = jt*32 + (r&3) + 8*(r>>2) + 4*hi2 ----
  uint mu[16];
  const uint8_t* mrow = (const uint8_t*)x3 + qrow * LK;
  if (byteMode) {
    #pragma unroll
    for (int jt = 0; jt < 4; ++jt)
      #pragma unroll
      for (int rg = 0; rg < 4; ++rg)
        mu[jt * 4 + rg] = *(const uint*)(mrow + jt * 32 + 8 * rg + 4 * hi2);
  }

  // ---- build M (waves 0-3) / V (waves 4-7): per wave 32 x2-rows, 4 n-tiles ----
  {
    const int wb = w & 3;
    bf16x8 axf[8];    // A = x2 rows 32*wb + q31
    const float* x2r = x2 + ((size_t)b * LK + 32 * wb + q31) * H;
    #pragma unroll
    for (int kt = 0; kt < 8; ++kt)
      axf[kt] = cvt_frag(x2r + kt * 16 + 8 * hi2);

    if (w < 4) {
      const bf16_t* W2T = (const bf16_t*)(ws + WS_W2T);
      #pragma unroll
      for (int nt = 0; nt < 4; ++nt) {
        f32x16 c = zero16();
        #pragma unroll
        for (int kt = 0; kt < 8; ++kt)
          c = MFMA32(axf[kt],
                     *(const bf16x8*)(W2T + (size_t)(nt * 32 + q31) * H + kt * 16 + 8 * hi2), c);
        #pragma unroll
        for (int r = 0; r < 16; ++r)
          *(bf16_t*)(sM + swz(32 * wb + (r & 3) + 8 * (r >> 2) + 4 * hi2,
                              (nt * 32 + q31) * 2)) = (bf16_t)c[r];
      }
    } else {
      #pragma unroll
      for (int nt = 0; nt < 4; ++nt) {
        f32x16 c = zero16();
        #pragma unroll
        for (int kt = 0; kt < 8; ++kt)
          c = MFMA32(axf[kt],
                     cvt_frag(wv + (size_t)(nt * 32 + q31) * H + kt * 16 + 8 * hi2), c);
        #pragma unroll
        for (int r = 0; r < 16; ++r)
          *(bf16_t*)(sV + swz(32 * wb + (r & 3) + 8 * (r >> 2) + 4 * hi2,
                              (nt * 32 + q31) * 2)) = (bf16_t)c[r];
      }
    }
  }
  __syncthreads();

  // ---- S^T = M @ x1^T: D[j][q], col q = q31 (lane-local q!) ----
  f32x16 sj[4];
  #pragma unroll
  for (int jt = 0; jt < 4; ++jt) sj[jt] = zero16();
  #pragma unroll
  for (int kt = 0; kt < 8; ++kt)
    #pragma unroll
    for (int jt = 0; jt < 4; ++jt)
      sj[jt] = MFMA32(*(const bf16x8*)(sM + swz(jt * 32 + q31, kt * 32 + hi2 * 16)),
                      xb[kt], sj[jt]);

  // ---- p = exp2(S*C1), masked (shift-free softmax, validated round 4) ----
  const uint* mrowW = (const uint*)x3 + qrow * LK;
  #pragma unroll
  for (int jt = 0; jt < 4; ++jt) {
    #pragma unroll
    for (int rg = 0; rg < 4; ++rg) {
      uint m0, m1, m2, m3;
      if (byteMode) {
        uint u = mu[jt * 4 + rg];
        m0 = u & 0xffu; m1 = (u >> 8) & 0xffu; m2 = (u >> 16) & 0xffu; m3 = u >> 24;
      } else {
        uint4 mw = *(const uint4*)(mrowW + jt * 32 + 8 * rg + 4 * hi2);
        m0 = mw.x; m1 = mw.y; m2 = mw.z; m3 = mw.w;
      }
      float p0 = __builtin_amdgcn_exp2f(sj[jt][rg * 4 + 0] * C1);
      float p1 = __builtin_amdgcn_exp2f(sj[jt][rg * 4 + 1] * C1);
      float p2 = __builtin_amdgcn_exp2f(sj[jt][rg * 4 + 2] * C1);
      float p3 = __builtin_amdgcn_exp2f(sj[jt][rg * 4 + 3] * C1);
      sj[jt][rg * 4 + 0] = m0 ? 0.f : p0;
      sj[jt][rg * 4 + 1] = m1 ? 0.f : p1;
      sj[jt][rg * 4 + 2] = m2 ? 0.f : p2;
      sj[jt][rg * 4 + 3] = m3 ? 0.f : p3;
    }
  }

  // ---- build P^T B-frags in-register: cvt_pk pairs + permlane32_swap.
  // C rows per lane (tile jt): j = (r&3) + 8*(r>>2) + 4*hi2.
  // B-frag pb[2jt+h] wants j = 16*(2jt+h) ... lane half 8*hi2 + e.
  // swap(A=pk(c0,c1), B=pk(c4,c5)): A' = own lo-j pair / partner c4c5;
  // B' = partner c0c1 / own c4c5  -> exactly the missing halves.
  bf16x8 pb[8];
  #pragma unroll
  for (int jt = 0; jt < 4; ++jt) {
    #pragma unroll
    for (int h = 0; h < 2; ++h) {
      uint A = pkbf(sj[jt][h * 8 + 0], sj[jt][h * 8 + 1]);
      uint C = pkbf(sj[jt][h * 8 + 2], sj[jt][h * 8 + 3]);
      uint B = pkbf(sj[jt][h * 8 + 4], sj[jt][h * 8 + 5]);
      uint D = pkbf(sj[jt][h * 8 + 6], sj[jt][h * 8 + 7]);
      asm("v_permlane32_swap_b32 %0, %1" : "+v"(A), "+v"(B));
      asm("v_permlane32_swap_b32 %0, %1" : "+v"(C), "+v"(D));
      union { uint u[4]; bf16x8 v; } pu;
      pu.u[0] = A; pu.u[1] = C; pu.u[2] = B; pu.u[3] = D;
      pb[jt * 2 + h] = pu.v;
    }
  }

  // ---- dsum[q] via ones-A MFMA on the same bf16 pb (all D rows = dsum) ----
  bf16x8 ones1;
  #pragma unroll
  for (int e = 0; e < 8; ++e) ones1[e] = (bf16_t)1.f;
  f32x16 dacc = zero16();
  #pragma unroll
  for (int kt = 0; kt < 8; ++kt)
    dacc = MFMA32(ones1, pb[kt], dacc);

  // ---- O[i][q] = V @ P^T ----
  f32x16 oc[4];
  #pragma unroll
  for (int it = 0; it < 4; ++it) oc[it] = zero16();
  #pragma unroll
  for (int kt = 0; kt < 8; ++kt)
    #pragma unroll
    for (int it = 0; it < 4; ++it)
      oc[it] = MFMA32(*(const bf16x8*)(sV + swz(it * 32 + q31, kt * 32 + hi2 * 16)),
                      pb[kt], oc[it]);

  const float inv = 1.0f / dacc[0];

  // ---- stores: per (it,r): lanes = 2 i-rows x 32 consecutive q = full 128B lines
  #pragma unroll
  for (int it = 0; it < 4; ++it)
    #pragma unroll
    for (int r = 0; r < 16; ++r) {
      const int i = it * 32 + (r & 3) + 8 * (r >> 2) + 4 * hi2;
      out[((size_t)b * LK + i) * LQ + q0w + q31] = oc[it][r] * inv;
    }
}

extern "C" void kernel_launch(void* const* d_in, const int* in_sizes, int n_in,
                              void* d_out, int out_size, void* d_ws, size_t ws_size,
                              hipStream_t stream) {
  const float* x1 = (const float*)d_in[0];
  const float* x2 = (const float*)d_in[1];
  const void*  x3 = d_in[2];
  const float* wq = (const float*)d_in[3];
  const float* wk = (const float*)d_in[4];
  const float* wv = (const float*)d_in[5];
  uint8_t* ws = (uint8_t*)d_ws;
  float* out = (float*)d_out;

  prep0_kernel<<<1, 512, 0, stream>>>(wq, wk, (const unsigned*)x3, ws);
  attn_kernel<<<NB * (LQ / 256), 512, 0, stream>>>(x1, x2, wv, x3, ws, out);
}

// Round 6
// 70.987 us; speedup vs baseline: 1.3418x; 1.3418x over previous
//
#include <hip/hip_runtime.h>
#include <hip/hip_bf16.h>
#include <stdint.h>

typedef __bf16 bf16_t;
typedef __bf16 bf16x8 __attribute__((ext_vector_type(8)));
typedef float  f32x4  __attribute__((ext_vector_type(4)));
typedef float  f32x16 __attribute__((ext_vector_type(16)));
typedef unsigned int uint;
typedef uint uintx4 __attribute__((ext_vector_type(4)));

#define MFMA16(a,b,c) __builtin_amdgcn_mfma_f32_16x16x32_bf16((a),(b),(c),0,0,0)
#define MFMA32(a,b,c) __builtin_amdgcn_mfma_f32_32x32x16_bf16((a),(b),(c),0,0,0)

constexpr int NB = 16;
constexpr int LQ = 8192;
constexpr int LK = 128;
constexpr int H  = 128;

// log2(e) / sqrt(H): fold softmax scale + exp2 conversion into one multiply
constexpr float C1 = 1.4426950408889634f / 11.313708498984761f;

constexpr size_t WS_FLAG = 0;
constexpr size_t WS_W2T  = 1024;    // (wq^T wk), 128x128 bf16 row-major

// XOR swizzle for [*][128] bf16 LDS tiles (row stride 256 B)
__device__ __forceinline__ unsigned swz(unsigned row, unsigned byte) {
  return row * 256u + (byte ^ ((row & 15u) << 4));
}

__device__ __forceinline__ bf16x8 cvt_frag(const float* p) {
  f32x4 u0 = *(const f32x4*)p;
  f32x4 u1 = *(const f32x4*)(p + 4);
  bf16x8 v;
  #pragma unroll
  for (int e = 0; e < 4; ++e) { v[e] = (bf16_t)u0[e]; v[e + 4] = (bf16_t)u1[e]; }
  return v;
}

__device__ __forceinline__ f32x16 zero16() {
  f32x16 z;
  #pragma unroll
  for (int i = 0; i < 16; ++i) z[i] = 0.f;
  return z;
}

// v_cvt_pk_bf16_f32: lo = bf16(a), hi = bf16(b)
__device__ __forceinline__ uint pkbf(float a, float b) {
  uint d;
  asm("v_cvt_pk_bf16_f32 %0, %1, %2" : "=v"(d) : "v"(a), "v"(b));
  return d;
}

// ---------------------------------------------------------------------------
// prep0 (1 block): W2T = wq^T @ wk (bf16 to ws) + mask dtype probe
// ---------------------------------------------------------------------------
__global__ __launch_bounds__(512) void prep0_kernel(
    const float* __restrict__ wq, const float* __restrict__ wk,
    const unsigned* __restrict__ x3w, uint8_t* __restrict__ ws)
{
  __shared__ uint8_t sT[65536];   // wqT | wkT, each [128][128] bf16 swizzled
  const int tid = threadIdx.x;
  const int row = tid >> 2, c0 = (tid & 3) * 32;

  #pragma unroll
  for (int which = 0; which < 2; ++which) {
    const float* W = which ? wk : wq;
    uint8_t* dst = sT + which * 32768;
    const float* s = W + row * H + c0;
    #pragma unroll
    for (int j = 0; j < 32; ++j)
      *(bf16_t*)(dst + swz(c0 + j, row * 2)) = (bf16_t)s[j];
  }

  __shared__ int sF32, sBig;
  if (tid == 0) { sF32 = 0; sBig = 0; }
  __syncthreads();
  {
    int f = 0, g = 0;
    #pragma unroll
    for (int j = 0; j < 4; ++j) {
      unsigned v = x3w[tid * 4 + j];
      if (v == 0x3f800000u) f = 1;
      else if (v > 1u) g = 1;
    }
    if (f) sF32 = 1;
    if (g) sBig = 1;
  }
  __syncthreads();
  if (tid == 0) *(int*)(ws + WS_FLAG) = (sF32 == 0 && sBig == 1) ? 1 : 0;

  // W2T[i][j] = sum_k wq[k][i] wk[k][j]
  const int lane = tid & 63, w = tid >> 6, lo = lane & 15, hi = lane >> 4;
  bf16x8 a[4];
  #pragma unroll
  for (int kk = 0; kk < 4; ++kk)
    a[kk] = *(const bf16x8*)(sT + swz(16 * w + lo, kk * 64 + hi * 16));
  bf16_t* W2T = (bf16_t*)(ws + WS_W2T);
  #pragma unroll
  for (int t = 0; t < 8; ++t) {
    f32x4 c = {0.f, 0.f, 0.f, 0.f};
    #pragma unroll
    for (int kk = 0; kk < 4; ++kk)
      c = MFMA16(a[kk], *(const bf16x8*)(sT + 32768 + swz(16 * t + lo, kk * 64 + hi * 16)), c);
    #pragma unroll
    for (int r = 0; r < 4; ++r)
      W2T[(16 * w + hi * 4 + r) * H + 16 * t + lo] = (bf16_t)c[r];
  }
}

// ---------------------------------------------------------------------------
// Main fused kernel, 32x32x16 MFMA, transposed-S / in-register-P structure.
// Block = (batch b, 256-q chunk), 8 waves, grid 512, LDS 64 KB.
// Register-pressure-shaped: S-phase in two j-tile pairs (2 live f32x16),
// O-phase in two it-tile pairs with interleaved dsum chain.
// ---------------------------------------------------------------------------
__global__ __launch_bounds__(512, 2) void attn_kernel(
    const float* __restrict__ x1, const float* __restrict__ x2,
    const float* __restrict__ wv, const void* __restrict__ x3,
    const uint8_t* __restrict__ ws, float* __restrict__ out)
{
  __shared__ uint8_t sm[65536];
  uint8_t* sM = sm;            // M [128 j][128 c] bf16 swizzled
  uint8_t* sV = sm + 32768;    // V [128 i][128 j] bf16 swizzled

  const int tid = threadIdx.x, blk = blockIdx.x;
  const int b = blk >> 5, qc = (blk & 31) * 256;
  const int l = tid & 63, w = tid >> 6;
  const int q31 = l & 31, hi2 = l >> 5;
  const int byteMode = *(const int*)(ws + WS_FLAG);

  const int q0w = qc + w * 32;
  const size_t qrow = (size_t)b * LQ + q0w + q31;   // this lane's q row

  // ---- x1 B-frags: B[k][q]: n=q31, k = kt*16 + 8*hi2 + e ----
  bf16x8 xb[8];
  {
    const float* xr = x1 + qrow * H;
    #pragma unroll
    for (int kt = 0; kt < 8; ++kt)
      xb[kt] = cvt_frag(xr + kt * 16 + 8 * hi2);
  }

  // ---- mask prefetch (byte mode): reg r of j-tile jt needs byte
  //      j = jt*32 + (r&3) + 8*(r>>2) + 4*hi2 ----
  uint mu[16];
  const uint8_t* mrow = (const uint8_t*)x3 + qrow * LK;
  if (byteMode) {
    #pragma unroll
    for (int jt = 0; jt < 4; ++jt)
      #pragma unroll
      for (int rg = 0; rg < 4; ++rg)
        mu[jt * 4 + rg] = *(const uint*)(mrow + jt * 32 + 8 * rg + 4 * hi2);
  }

  // ---- build M (waves 0-3) / V (waves 4-7): per wave 32 x2-rows, 4 n-tiles ----
  {
    const int wb = w & 3;
    bf16x8 axf[8];    // A = x2 rows 32*wb + q31
    const float* x2r = x2 + ((size_t)b * LK + 32 * wb + q31) * H;
    #pragma unroll
    for (int kt = 0; kt < 8; ++kt)
      axf[kt] = cvt_frag(x2r + kt * 16 + 8 * hi2);

    if (w < 4) {
      const bf16_t* W2T = (const bf16_t*)(ws + WS_W2T);
      #pragma unroll
      for (int nt = 0; nt < 4; ++nt) {
        f32x16 c = zero16();
        #pragma unroll
        for (int kt = 0; kt < 8; ++kt)
          c = MFMA32(axf[kt],
                     *(const bf16x8*)(W2T + (size_t)(nt * 32 + q31) * H + kt * 16 + 8 * hi2), c);
        #pragma unroll
        for (int r = 0; r < 16; ++r)
          *(bf16_t*)(sM + swz(32 * wb + (r & 3) + 8 * (r >> 2) + 4 * hi2,
                              (nt * 32 + q31) * 2)) = (bf16_t)c[r];
      }
    } else {
      #pragma unroll
      for (int nt = 0; nt < 4; ++nt) {
        f32x16 c = zero16();
        #pragma unroll
        for (int kt = 0; kt < 8; ++kt)
          c = MFMA32(axf[kt],
                     cvt_frag(wv + (size_t)(nt * 32 + q31) * H + kt * 16 + 8 * hi2), c);
        #pragma unroll
        for (int r = 0; r < 16; ++r)
          *(bf16_t*)(sV + swz(32 * wb + (r & 3) + 8 * (r >> 2) + 4 * hi2,
                              (nt * 32 + q31) * 2)) = (bf16_t)c[r];
      }
    }
  }
  __syncthreads();

  // ---- S^T = M @ x1^T in two j-tile pairs; pack to bf16 pb-frags at once ----
  const uint* mrowW = (const uint*)x3 + qrow * LK;
  bf16x8 pb[8];

  #pragma unroll
  for (int half = 0; half < 2; ++half) {
    const int jt0 = half * 2, jt1 = half * 2 + 1;
    f32x16 s0 = zero16(), s1 = zero16();
    #pragma unroll
    for (int kt = 0; kt < 8; ++kt) {
      s0 = MFMA32(*(const bf16x8*)(sM + swz(jt0 * 32 + q31, kt * 32 + hi2 * 16)),
                  xb[kt], s0);
      s1 = MFMA32(*(const bf16x8*)(sM + swz(jt1 * 32 + q31, kt * 32 + hi2 * 16)),
                  xb[kt], s1);
    }

    // p = exp2(S*C1), masked (shift-free softmax, validated r4/r5)
    #pragma unroll
    for (int jj = 0; jj < 2; ++jj) {
      f32x16& sj = jj ? s1 : s0;
      const int jt = half * 2 + jj;
      #pragma unroll
      for (int rg = 0; rg < 4; ++rg) {
        uint m0, m1, m2, m3;
        if (byteMode) {
          uint u = mu[jt * 4 + rg];
          m0 = u & 0xffu; m1 = (u >> 8) & 0xffu; m2 = (u >> 16) & 0xffu; m3 = u >> 24;
        } else {
          uint4 mw = *(const uint4*)(mrowW + jt * 32 + 8 * rg + 4 * hi2);
          m0 = mw.x; m1 = mw.y; m2 = mw.z; m3 = mw.w;
        }
        float p0 = __builtin_amdgcn_exp2f(sj[rg * 4 + 0] * C1);
        float p1 = __builtin_amdgcn_exp2f(sj[rg * 4 + 1] * C1);
        float p2 = __builtin_amdgcn_exp2f(sj[rg * 4 + 2] * C1);
        float p3 = __builtin_amdgcn_exp2f(sj[rg * 4 + 3] * C1);
        sj[rg * 4 + 0] = m0 ? 0.f : p0;
        sj[rg * 4 + 1] = m1 ? 0.f : p1;
        sj[rg * 4 + 2] = m2 ? 0.f : p2;
        sj[rg * 4 + 3] = m3 ? 0.f : p3;
      }

      // P^T B-frags in-register: cvt_pk pairs + permlane32_swap
      #pragma unroll
      for (int h = 0; h < 2; ++h) {
        uint A = pkbf(sj[h * 8 + 0], sj[h * 8 + 1]);
        uint C = pkbf(sj[h * 8 + 2], sj[h * 8 + 3]);
        uint B = pkbf(sj[h * 8 + 4], sj[h * 8 + 5]);
        uint D = pkbf(sj[h * 8 + 6], sj[h * 8 + 7]);
        asm("v_permlane32_swap_b32 %0, %1" : "+v"(A), "+v"(B));
        asm("v_permlane32_swap_b32 %0, %1" : "+v"(C), "+v"(D));
        uintx4 t; t.x = A; t.y = C; t.z = B; t.w = D;
        pb[jt * 2 + h] = __builtin_bit_cast(bf16x8, t);
      }
    }
  }

  // ---- dsum chain + first oc pair (3 independent MFMA chains) ----
  bf16x8 ones1;
  #pragma unroll
  for (int e = 0; e < 8; ++e) ones1[e] = (bf16_t)1.f;

  f32x16 dacc = zero16();
  {
    f32x16 o0 = zero16(), o1 = zero16();
    #pragma unroll
    for (int kt = 0; kt < 8; ++kt) {
      dacc = MFMA32(ones1, pb[kt], dacc);
      o0 = MFMA32(*(const bf16x8*)(sV + swz(0 * 32 + q31, kt * 32 + hi2 * 16)), pb[kt], o0);
      o1 = MFMA32(*(const bf16x8*)(sV + swz(1 * 32 + q31, kt * 32 + hi2 * 16)), pb[kt], o1);
    }
    const float inv = 1.0f / dacc[0];
    #pragma unroll
    for (int r = 0; r < 16; ++r) {
      const int ibase = (r & 3) + 8 * (r >> 2) + 4 * hi2;
      out[((size_t)b * LK + ibase) * LQ + q0w + q31] = o0[r] * inv;
      out[((size_t)b * LK + 32 + ibase) * LQ + q0w + q31] = o1[r] * inv;
    }
  }

  // ---- second oc pair ----
  {
    const float inv = 1.0f / dacc[0];
    f32x16 o2 = zero16(), o3 = zero16();
    #pragma unroll
    for (int kt = 0; kt < 8; ++kt) {
      o2 = MFMA32(*(const bf16x8*)(sV + swz(2 * 32 + q31, kt * 32 + hi2 * 16)), pb[kt], o2);
      o3 = MFMA32(*(const bf16x8*)(sV + swz(3 * 32 + q31, kt * 32 + hi2 * 16)), pb[kt], o3);
    }
    #pragma unroll
    for (int r = 0; r < 16; ++r) {
      const int ibase = (r & 3) + 8 * (r >> 2) + 4 * hi2;
      out[((size_t)b * LK + 64 + ibase) * LQ + q0w + q31] = o2[r] * inv;
      out[((size_t)b * LK + 96 + ibase) * LQ + q0w + q31] = o3[r] * inv;
    }
  }
}

extern "C" void kernel_launch(void* const* d_in, const int* in_sizes, int n_in,
                              void* d_out, int out_size, void* d_ws, size_t ws_size,
                              hipStream_t stream) {
  const float* x1 = (const float*)d_in[0];
  const float* x2 = (const float*)d_in[1];
  const void*  x3 = d_in[2];
  const float* wq = (const float*)d_in[3];
  const float* wk = (const float*)d_in[4];
  const float* wv = (const float*)d_in[5];
  uint8_t* ws = (uint8_t*)d_ws;
  float* out = (float*)d_out;

  prep0_kernel<<<1, 512, 0, stream>>>(wq, wk, (const unsigned*)x3, ws);
  attn_kernel<<<NB * (LQ / 256), 512, 0, stream>>>(x1, x2, wv, x3, ws, out);
}

// Round 7
// 56.851 us; speedup vs baseline: 1.6754x; 1.2486x over previous
//
#include <hip/hip_runtime.h>
#include <hip/hip_bf16.h>
#include <stdint.h>

typedef __bf16 bf16_t;
typedef __bf16 bf16x8 __attribute__((ext_vector_type(8)));
typedef float  f32x4  __attribute__((ext_vector_type(4)));
typedef float  f32x16 __attribute__((ext_vector_type(16)));
typedef unsigned int uint;
typedef uint uintx4 __attribute__((ext_vector_type(4)));

#define MFMA16(a,b,c) __builtin_amdgcn_mfma_f32_16x16x32_bf16((a),(b),(c),0,0,0)
#define MFMA32(a,b,c) __builtin_amdgcn_mfma_f32_32x32x16_bf16((a),(b),(c),0,0,0)

constexpr int NB = 16;
constexpr int LQ = 8192;
constexpr int LK = 128;
constexpr int H  = 128;

// log2(e) / sqrt(H): fold softmax scale + exp2 conversion into one multiply
constexpr float C1 = 1.4426950408889634f / 11.313708498984761f;

constexpr size_t WS_FLAG = 0;
constexpr size_t WS_W2T  = 1024;    // (wq^T wk), 128x128 bf16 row-major

// XOR swizzle for [*][128] bf16 LDS tiles (row stride 256 B)
__device__ __forceinline__ unsigned swz(unsigned row, unsigned byte) {
  return row * 256u + (byte ^ ((row & 15u) << 4));
}

__device__ __forceinline__ bf16x8 cvt_frag(const float* p) {
  f32x4 u0 = *(const f32x4*)p;
  f32x4 u1 = *(const f32x4*)(p + 4);
  bf16x8 v;
  #pragma unroll
  for (int e = 0; e < 4; ++e) { v[e] = (bf16_t)u0[e]; v[e + 4] = (bf16_t)u1[e]; }
  return v;
}

__device__ __forceinline__ f32x16 zero16() {
  f32x16 z;
  #pragma unroll
  for (int i = 0; i < 16; ++i) z[i] = 0.f;
  return z;
}

// v_cvt_pk_bf16_f32: lo = bf16(a), hi = bf16(b)
__device__ __forceinline__ uint pkbf(float a, float b) {
  uint d;
  asm("v_cvt_pk_bf16_f32 %0, %1, %2" : "=v"(d) : "v"(a), "v"(b));
  return d;
}

// ---------------------------------------------------------------------------
// prep0 (1 block): W2T = wq^T @ wk (bf16 to ws) + mask dtype probe
// ---------------------------------------------------------------------------
__global__ __launch_bounds__(512) void prep0_kernel(
    const float* __restrict__ wq, const float* __restrict__ wk,
    const unsigned* __restrict__ x3w, uint8_t* __restrict__ ws)
{
  __shared__ uint8_t sT[65536];   // wqT | wkT, each [128][128] bf16 swizzled
  const int tid = threadIdx.x;
  const int row = tid >> 2, c0 = (tid & 3) * 32;

  #pragma unroll
  for (int which = 0; which < 2; ++which) {
    const float* W = which ? wk : wq;
    uint8_t* dst = sT + which * 32768;
    const float* s = W + row * H + c0;
    #pragma unroll
    for (int j = 0; j < 32; ++j)
      *(bf16_t*)(dst + swz(c0 + j, row * 2)) = (bf16_t)s[j];
  }

  __shared__ int sF32, sBig;
  if (tid == 0) { sF32 = 0; sBig = 0; }
  __syncthreads();
  {
    int f = 0, g = 0;
    #pragma unroll
    for (int j = 0; j < 4; ++j) {
      unsigned v = x3w[tid * 4 + j];
      if (v == 0x3f800000u) f = 1;
      else if (v > 1u) g = 1;
    }
    if (f) sF32 = 1;
    if (g) sBig = 1;
  }
  __syncthreads();
  if (tid == 0) *(int*)(ws + WS_FLAG) = (sF32 == 0 && sBig == 1) ? 1 : 0;

  // W2T[i][j] = sum_k wq[k][i] wk[k][j]
  const int lane = tid & 63, w = tid >> 6, lo = lane & 15, hi = lane >> 4;
  bf16x8 a[4];
  #pragma unroll
  for (int kk = 0; kk < 4; ++kk)
    a[kk] = *(const bf16x8*)(sT + swz(16 * w + lo, kk * 64 + hi * 16));
  bf16_t* W2T = (bf16_t*)(ws + WS_W2T);
  #pragma unroll
  for (int t = 0; t < 8; ++t) {
    f32x4 c = {0.f, 0.f, 0.f, 0.f};
    #pragma unroll
    for (int kk = 0; kk < 4; ++kk)
      c = MFMA16(a[kk], *(const bf16x8*)(sT + 32768 + swz(16 * t + lo, kk * 64 + hi * 16)), c);
    #pragma unroll
    for (int r = 0; r < 4; ++r)
      W2T[(16 * w + hi * 4 + r) * H + 16 * t + lo] = (bf16_t)c[r];
  }
}

// ---------------------------------------------------------------------------
// Main fused kernel (r6 math, software-pipelined for memory concurrency).
// Grid 256 = 1 block/CU; 8 waves; __launch_bounds__(512,2) -> 256-VGPR budget.
// Each wave owns 64 q rows = 2 subtiles of 32. Iter-1's raw f32 x1 tile +
// mask are issued BEFORE iter-0's compute, so each wave keeps ~20 KB of
// loads in flight while MFMAs run (Little's law: need ~9 KB/CU for peak).
// ---------------------------------------------------------------------------
__global__ __launch_bounds__(512, 2) void attn_kernel(
    const float* __restrict__ x1, const float* __restrict__ x2,
    const float* __restrict__ wv, const void* __restrict__ x3,
    const uint8_t* __restrict__ ws, float* __restrict__ out)
{
  __shared__ uint8_t sm[65536];
  uint8_t* sM = sm;            // M [128 j][128 c] bf16 swizzled
  uint8_t* sV = sm + 32768;    // V [128 i][128 j] bf16 swizzled

  const int tid = threadIdx.x, blk = blockIdx.x;
  const int b = blk >> 4, qc = (blk & 15) * 512;
  const int l = tid & 63, w = tid >> 6;
  const int q31 = l & 31, hi2 = l >> 5;
  const int byteMode = *(const int*)(ws + WS_FLAG);

  // wave w owns rows [qc + w*64, +64); subtile ii at +32*ii
  const int q0base = qc + w * 64;
  const size_t qrow0 = (size_t)b * LQ + q0base + q31;

  // ---- issue iter-0 x1 raw loads + mask ----
  f32x4 xraw[2][16];
  uint mu[2][16];
  {
    const float* p = x1 + qrow0 * H;
    #pragma unroll
    for (int kt = 0; kt < 8; ++kt) {
      xraw[0][2 * kt]     = *(const f32x4*)(p + kt * 16 + 8 * hi2);
      xraw[0][2 * kt + 1] = *(const f32x4*)(p + kt * 16 + 8 * hi2 + 4);
    }
    if (byteMode) {
      const uint8_t* mp = (const uint8_t*)x3 + qrow0 * LK;
      #pragma unroll
      for (int jt = 0; jt < 4; ++jt)
        #pragma unroll
        for (int rg = 0; rg < 4; ++rg)
          mu[0][jt * 4 + rg] = *(const uint*)(mp + jt * 32 + 8 * rg + 4 * hi2);
    }
  }

  // ---- build M (waves 0-3) / V (waves 4-7) ----
  {
    const int wb = w & 3;
    bf16x8 axf[8];    // A = x2 rows 32*wb + q31
    const float* x2r = x2 + ((size_t)b * LK + 32 * wb + q31) * H;
    #pragma unroll
    for (int kt = 0; kt < 8; ++kt)
      axf[kt] = cvt_frag(x2r + kt * 16 + 8 * hi2);

    if (w < 4) {
      const bf16_t* W2T = (const bf16_t*)(ws + WS_W2T);
      #pragma unroll
      for (int nt = 0; nt < 4; ++nt) {
        f32x16 c = zero16();
        #pragma unroll
        for (int kt = 0; kt < 8; ++kt)
          c = MFMA32(axf[kt],
                     *(const bf16x8*)(W2T + (size_t)(nt * 32 + q31) * H + kt * 16 + 8 * hi2), c);
        #pragma unroll
        for (int r = 0; r < 16; ++r)
          *(bf16_t*)(sM + swz(32 * wb + (r & 3) + 8 * (r >> 2) + 4 * hi2,
                              (nt * 32 + q31) * 2)) = (bf16_t)c[r];
      }
    } else {
      #pragma unroll
      for (int nt = 0; nt < 4; ++nt) {
        f32x16 c = zero16();
        #pragma unroll
        for (int kt = 0; kt < 8; ++kt)
          c = MFMA32(axf[kt],
                     cvt_frag(wv + (size_t)(nt * 32 + q31) * H + kt * 16 + 8 * hi2), c);
        #pragma unroll
        for (int r = 0; r < 16; ++r)
          *(bf16_t*)(sV + swz(32 * wb + (r & 3) + 8 * (r >> 2) + 4 * hi2,
                              (nt * 32 + q31) * 2)) = (bf16_t)c[r];
      }
    }
  }
  __syncthreads();

  // ---- issue iter-1 x1 raw loads + mask (stay in flight through iter-0) ----
  {
    const float* p = x1 + (qrow0 + 32) * H;
    #pragma unroll
    for (int kt = 0; kt < 8; ++kt) {
      xraw[1][2 * kt]     = *(const f32x4*)(p + kt * 16 + 8 * hi2);
      xraw[1][2 * kt + 1] = *(const f32x4*)(p + kt * 16 + 8 * hi2 + 4);
    }
    if (byteMode) {
      const uint8_t* mp = (const uint8_t*)x3 + (qrow0 + 32) * LK;
      #pragma unroll
      for (int jt = 0; jt < 4; ++jt)
        #pragma unroll
        for (int rg = 0; rg < 4; ++rg)
          mu[1][jt * 4 + rg] = *(const uint*)(mp + jt * 32 + 8 * rg + 4 * hi2);
    }
  }

  bf16x8 ones1;
  #pragma unroll
  for (int e = 0; e < 8; ++e) ones1[e] = (bf16_t)1.f;

  // ---- two fully-unrolled subtile iterations ----
  #pragma unroll
  for (int ii = 0; ii < 2; ++ii) {
    const int q0w = q0base + ii * 32;
    const size_t qrow = qrow0 + ii * 32;

    // convert raw f32 -> bf16 B-frags (frees xraw[ii])
    bf16x8 xbf[8];
    #pragma unroll
    for (int kt = 0; kt < 8; ++kt)
      #pragma unroll
      for (int e = 0; e < 4; ++e) {
        xbf[kt][e]     = (bf16_t)xraw[ii][2 * kt][e];
        xbf[kt][e + 4] = (bf16_t)xraw[ii][2 * kt + 1][e];
      }

    // S^T = M @ x1^T in two j-tile pairs; pack to bf16 pb-frags
    const uint* mrowW = (const uint*)x3 + qrow * LK;
    bf16x8 pb[8];

    #pragma unroll
    for (int half = 0; half < 2; ++half) {
      const int jt0 = half * 2, jt1 = half * 2 + 1;
      f32x16 s0 = zero16(), s1 = zero16();
      #pragma unroll
      for (int kt = 0; kt < 8; ++kt) {
        s0 = MFMA32(*(const bf16x8*)(sM + swz(jt0 * 32 + q31, kt * 32 + hi2 * 16)),
                    xbf[kt], s0);
        s1 = MFMA32(*(const bf16x8*)(sM + swz(jt1 * 32 + q31, kt * 32 + hi2 * 16)),
                    xbf[kt], s1);
      }

      #pragma unroll
      for (int jj = 0; jj < 2; ++jj) {
        f32x16& sj = jj ? s1 : s0;
        const int jt = half * 2 + jj;
        #pragma unroll
        for (int rg = 0; rg < 4; ++rg) {
          uint m0, m1, m2, m3;
          if (byteMode) {
            uint u = mu[ii][jt * 4 + rg];
            m0 = u & 0xffu; m1 = (u >> 8) & 0xffu; m2 = (u >> 16) & 0xffu; m3 = u >> 24;
          } else {
            uint4 mw = *(const uint4*)(mrowW + jt * 32 + 8 * rg + 4 * hi2);
            m0 = mw.x; m1 = mw.y; m2 = mw.z; m3 = mw.w;
          }
          float p0 = __builtin_amdgcn_exp2f(sj[rg * 4 + 0] * C1);
          float p1 = __builtin_amdgcn_exp2f(sj[rg * 4 + 1] * C1);
          float p2 = __builtin_amdgcn_exp2f(sj[rg * 4 + 2] * C1);
          float p3 = __builtin_amdgcn_exp2f(sj[rg * 4 + 3] * C1);
          sj[rg * 4 + 0] = m0 ? 0.f : p0;
          sj[rg * 4 + 1] = m1 ? 0.f : p1;
          sj[rg * 4 + 2] = m2 ? 0.f : p2;
          sj[rg * 4 + 3] = m3 ? 0.f : p3;
        }

        // P^T B-frags in-register: cvt_pk pairs + permlane32_swap
        #pragma unroll
        for (int h = 0; h < 2; ++h) {
          uint A = pkbf(sj[h * 8 + 0], sj[h * 8 + 1]);
          uint C = pkbf(sj[h * 8 + 2], sj[h * 8 + 3]);
          uint B = pkbf(sj[h * 8 + 4], sj[h * 8 + 5]);
          uint D = pkbf(sj[h * 8 + 6], sj[h * 8 + 7]);
          asm("v_permlane32_swap_b32 %0, %1" : "+v"(A), "+v"(B));
          asm("v_permlane32_swap_b32 %0, %1" : "+v"(C), "+v"(D));
          uintx4 t; t.x = A; t.y = C; t.z = B; t.w = D;
          pb[jt * 2 + h] = __builtin_bit_cast(bf16x8, t);
        }
      }
    }

    // dsum chain + first oc pair (3 independent MFMA chains)
    f32x16 dacc = zero16();
    {
      f32x16 o0 = zero16(), o1 = zero16();
      #pragma unroll
      for (int kt = 0; kt < 8; ++kt) {
        dacc = MFMA32(ones1, pb[kt], dacc);
        o0 = MFMA32(*(const bf16x8*)(sV + swz(0 * 32 + q31, kt * 32 + hi2 * 16)), pb[kt], o0);
        o1 = MFMA32(*(const bf16x8*)(sV + swz(1 * 32 + q31, kt * 32 + hi2 * 16)), pb[kt], o1);
      }
      const float inv = 1.0f / dacc[0];
      #pragma unroll
      for (int r = 0; r < 16; ++r) {
        const int ibase = (r & 3) + 8 * (r >> 2) + 4 * hi2;
        out[((size_t)b * LK + ibase) * LQ + q0w + q31] = o0[r] * inv;
        out[((size_t)b * LK + 32 + ibase) * LQ + q0w + q31] = o1[r] * inv;
      }
    }

    // second oc pair
    {
      const float inv = 1.0f / dacc[0];
      f32x16 o2 = zero16(), o3 = zero16();
      #pragma unroll
      for (int kt = 0; kt < 8; ++kt) {
        o2 = MFMA32(*(const bf16x8*)(sV + swz(2 * 32 + q31, kt * 32 + hi2 * 16)), pb[kt], o2);
        o3 = MFMA32(*(const bf16x8*)(sV + swz(3 * 32 + q31, kt * 32 + hi2 * 16)), pb[kt], o3);
      }
      #pragma unroll
      for (int r = 0; r < 16; ++r) {
        const int ibase = (r & 3) + 8 * (r >> 2) + 4 * hi2;
        out[((size_t)b * LK + 64 + ibase) * LQ + q0w + q31] = o2[r] * inv;
        out[((size_t)b * LK + 96 + ibase) * LQ + q0w + q31] = o3[r] * inv;
      }
    }
  }
}

extern "C" void kernel_launch(void* const* d_in, const int* in_sizes, int n_in,
                              void* d_out, int out_size, void* d_ws, size_t ws_size,
                              hipStream_t stream) {
  const float* x1 = (const float*)d_in[0];
  const float* x2 = (const float*)d_in[1];
  const void*  x3 = d_in[2];
  const float* wq = (const float*)d_in[3];
  const float* wk = (const float*)d_in[4];
  const float* wv = (const float*)d_in[5];
  uint8_t* ws = (uint8_t*)d_ws;
  float* out = (float*)d_out;

  prep0_kernel<<<1, 512, 0, stream>>>(wq, wk, (const unsigned*)x3, ws);
  attn_kernel<<<NB * (LQ / 512), 512, 0, stream>>>(x1, x2, wv, x3, ws, out);
}

// Round 8
// 49.747 us; speedup vs baseline: 1.9147x; 1.1428x over previous
//
#include <hip/hip_runtime.h>
#include <hip/hip_bf16.h>
#include <stdint.h>

typedef __bf16 bf16_t;
typedef __bf16 bf16x8 __attribute__((ext_vector_type(8)));
typedef float  f32x4  __attribute__((ext_vector_type(4)));
typedef float  f32x16 __attribute__((ext_vector_type(16)));
typedef unsigned int uint;
typedef uint uintx4 __attribute__((ext_vector_type(4)));

#define MFMA16(a,b,c) __builtin_amdgcn_mfma_f32_16x16x32_bf16((a),(b),(c),0,0,0)
#define MFMA32(a,b,c) __builtin_amdgcn_mfma_f32_32x32x16_bf16((a),(b),(c),0,0,0)

constexpr int NB = 16;
constexpr int LQ = 8192;
constexpr int LK = 128;
constexpr int H  = 128;

// log2(e) / sqrt(H): fold softmax scale + exp2 conversion into one multiply
constexpr float C1 = 1.4426950408889634f / 11.313708498984761f;

constexpr size_t WS_FLAG = 0;
constexpr size_t WS_MV   = 1024;   // per batch: [M 32K | V 32K] swizzled bf16 LDS images

// XOR swizzle for [*][128] bf16 LDS tiles (row stride 256 B)
__device__ __forceinline__ unsigned swz(unsigned row, unsigned byte) {
  return row * 256u + (byte ^ ((row & 15u) << 4));
}

__device__ __forceinline__ bf16x8 cvt_frag(const float* p) {
  f32x4 u0 = *(const f32x4*)p;
  f32x4 u1 = *(const f32x4*)(p + 4);
  bf16x8 v;
  #pragma unroll
  for (int e = 0; e < 4; ++e) { v[e] = (bf16_t)u0[e]; v[e + 4] = (bf16_t)u1[e]; }
  return v;
}

__device__ __forceinline__ f32x16 zero16() {
  f32x16 z;
  #pragma unroll
  for (int i = 0; i < 16; ++i) z[i] = 0.f;
  return z;
}

// v_cvt_pk_bf16_f32: lo = bf16(a), hi = bf16(b)
__device__ __forceinline__ uint pkbf(float a, float b) {
  uint d;
  asm("v_cvt_pk_bf16_f32 %0, %1, %2" : "=v"(d) : "v"(a), "v"(b));
  return d;
}

// ---------------------------------------------------------------------------
// prep (32 blocks): block 2b   -> M_b = x2_b @ (wq^T wk)  (swizzled image to ws)
//                   block 2b+1 -> V_b = x2_b @ wv^T       (swizzled image to ws)
// Block 0 also runs the mask-dtype probe. Build code is r7's (validated),
// with W2T computed in-LDS by the M-blocks.
// ---------------------------------------------------------------------------
__global__ __launch_bounds__(512) void prep_kernel(
    const float* __restrict__ x2, const float* __restrict__ wq,
    const float* __restrict__ wk, const float* __restrict__ wv,
    const unsigned* __restrict__ x3w, uint8_t* __restrict__ ws)
{
  __shared__ uint8_t sP[131072];  // [wqT 32K | wkT 32K | W2T lin 32K | out 32K]
  __shared__ int sF32, sBig;
  const int tid = threadIdx.x;
  const int b = blockIdx.x >> 1, which = blockIdx.x & 1;
  const int l = tid & 63, w = tid >> 6, q31 = l & 31, hi2 = l >> 5;
  uint8_t* sOut = sP + 98304;

  if (which == 0) {
    if (blockIdx.x == 0) {
      // mask dtype probe over first 2048 words of x3:
      // int32 bool -> words in {0,1}; uint8 bool -> words like 0x01010101 (>1);
      // f32 bool -> words in {0, 0x3f800000}
      if (tid == 0) { sF32 = 0; sBig = 0; }
      __syncthreads();
      int f = 0, g = 0;
      #pragma unroll
      for (int j = 0; j < 4; ++j) {
        unsigned v = x3w[tid * 4 + j];
        if (v == 0x3f800000u) f = 1;
        else if (v > 1u) g = 1;
      }
      if (f) sF32 = 1;
      if (g) sBig = 1;
      __syncthreads();
      if (tid == 0) *(int*)(ws + WS_FLAG) = (sF32 == 0 && sBig == 1) ? 1 : 0;
    }

    // stage wqT / wkT swizzled
    {
      const int row = tid >> 2, c0 = (tid & 3) * 32;
      #pragma unroll
      for (int wh = 0; wh < 2; ++wh) {
        const float* W = wh ? wk : wq;
        uint8_t* dst = sP + wh * 32768;
        const float* s = W + row * H + c0;
        #pragma unroll
        for (int j = 0; j < 32; ++j)
          *(bf16_t*)(dst + swz(c0 + j, row * 2)) = (bf16_t)s[j];
      }
    }
    __syncthreads();

    // W2T[i][j] = sum_k wq[k][i] wk[k][j]  -> LDS linear [128][128] bf16
    {
      const int lo = l & 15, hi = l >> 4;
      bf16x8 a4[4];
      #pragma unroll
      for (int kk = 0; kk < 4; ++kk)
        a4[kk] = *(const bf16x8*)(sP + swz(16 * w + lo, kk * 64 + hi * 16));
      bf16_t* W2T = (bf16_t*)(sP + 65536);
      #pragma unroll
      for (int t = 0; t < 8; ++t) {
        f32x4 c = {0.f, 0.f, 0.f, 0.f};
        #pragma unroll
        for (int kk = 0; kk < 4; ++kk)
          c = MFMA16(a4[kk], *(const bf16x8*)(sP + 32768 + swz(16 * t + lo, kk * 64 + hi * 16)), c);
        #pragma unroll
        for (int r = 0; r < 4; ++r)
          W2T[(16 * w + hi * 4 + r) * H + 16 * t + lo] = (bf16_t)c[r];
      }
    }
    __syncthreads();

    // M build (r7 w<4 branch, W2T from LDS)
    if (w < 4) {
      const int wb = w;
      bf16x8 axf[8];
      const float* x2r = x2 + ((size_t)b * LK + 32 * wb + q31) * H;
      #pragma unroll
      for (int kt = 0; kt < 8; ++kt)
        axf[kt] = cvt_frag(x2r + kt * 16 + 8 * hi2);
      const bf16_t* W2Tl = (const bf16_t*)(sP + 65536);
      #pragma unroll
      for (int nt = 0; nt < 4; ++nt) {
        f32x16 c = zero16();
        #pragma unroll
        for (int kt = 0; kt < 8; ++kt)
          c = MFMA32(axf[kt],
                     *(const bf16x8*)(W2Tl + (size_t)(nt * 32 + q31) * H + kt * 16 + 8 * hi2), c);
        #pragma unroll
        for (int r = 0; r < 16; ++r)
          *(bf16_t*)(sOut + swz(32 * wb + (r & 3) + 8 * (r >> 2) + 4 * hi2,
                                (nt * 32 + q31) * 2)) = (bf16_t)c[r];
      }
    }
  } else {
    // V build (r7 w>=4 branch)
    if (w < 4) {
      const int wb = w;
      bf16x8 axf[8];
      const float* x2r = x2 + ((size_t)b * LK + 32 * wb + q31) * H;
      #pragma unroll
      for (int kt = 0; kt < 8; ++kt)
        axf[kt] = cvt_frag(x2r + kt * 16 + 8 * hi2);
      #pragma unroll
      for (int nt = 0; nt < 4; ++nt) {
        f32x16 c = zero16();
        #pragma unroll
        for (int kt = 0; kt < 8; ++kt)
          c = MFMA32(axf[kt],
                     cvt_frag(wv + (size_t)(nt * 32 + q31) * H + kt * 16 + 8 * hi2), c);
        #pragma unroll
        for (int r = 0; r < 16; ++r)
          *(bf16_t*)(sOut + swz(32 * wb + (r & 3) + 8 * (r >> 2) + 4 * hi2,
                                (nt * 32 + q31) * 2)) = (bf16_t)c[r];
      }
    }
  }
  __syncthreads();

  // copy the 32 KB swizzled image to ws (linear)
  {
    const uint4* src = (const uint4*)sOut;
    uint4* dst = (uint4*)(ws + WS_MV + (size_t)b * 65536 + (size_t)which * 32768);
    #pragma unroll
    for (int j = 0; j < 4; ++j)
      dst[tid + j * 512] = src[tid + j * 512];
  }
}

// ---------------------------------------------------------------------------
// Main fused kernel. Grid 512 (16 b x 32 chunks of 256 q rows); 8 waves;
// one 32-row subtile per wave; __launch_bounds__(512,4) -> VGPR<=128 ->
// 2 blocks/CU = 16 waves/CU (the VGPR limit exactly).
// Prologue: M/V image copy (ws->LDS) + x1 frags + mask all in flight before
// the single barrier; compute is the validated r6/r7 math.
// ---------------------------------------------------------------------------
__global__ __launch_bounds__(512, 4) void attn_kernel(
    const float* __restrict__ x1, const void* __restrict__ x3,
    const uint8_t* __restrict__ ws, float* __restrict__ out)
{
  __shared__ uint8_t sm[65536];
  uint8_t* sM = sm;            // M [128 j][128 c] bf16 swizzled
  uint8_t* sV = sm + 32768;    // V [128 i][128 j] bf16 swizzled

  const int tid = threadIdx.x, blk = blockIdx.x;
  const int b = blk >> 5, qc = (blk & 31) * 256;
  const int l = tid & 63, w = tid >> 6;
  const int q31 = l & 31, hi2 = l >> 5;
  const int byteMode = *(const int*)(ws + WS_FLAG);

  const int q0w = qc + w * 32;
  const size_t qrow = (size_t)b * LQ + q0w + q31;   // this lane's q row

  // ---- M/V image loads (64 KB; L2-resident after first block per batch) ----
  uint4 cp[8];
  {
    const uint4* mvsrc = (const uint4*)(ws + WS_MV + (size_t)b * 65536);
    #pragma unroll
    for (int j = 0; j < 8; ++j)
      cp[j] = mvsrc[tid + j * 512];
  }

  // ---- x1 B-frags: B[k][q]: n=q31, k = kt*16 + 8*hi2 + e ----
  bf16x8 xbf[8];
  {
    const float* xr = x1 + qrow * H;
    #pragma unroll
    for (int kt = 0; kt < 8; ++kt)
      xbf[kt] = cvt_frag(xr + kt * 16 + 8 * hi2);
  }

  // ---- mask prefetch (byte mode) ----
  uint mu[16];
  if (byteMode) {
    const uint8_t* mp = (const uint8_t*)x3 + qrow * LK;
    #pragma unroll
    for (int jt = 0; jt < 4; ++jt)
      #pragma unroll
      for (int rg = 0; rg < 4; ++rg)
        mu[jt * 4 + rg] = *(const uint*)(mp + jt * 32 + 8 * rg + 4 * hi2);
  }

  // ---- write M/V image into LDS ----
  {
    uint4* ldst = (uint4*)sm;
    #pragma unroll
    for (int j = 0; j < 8; ++j)
      ldst[tid + j * 512] = cp[j];
  }
  __syncthreads();

  // ---- S^T = M @ x1^T in two j-tile pairs; pack to bf16 pb-frags ----
  const uint* mrowW = (const uint*)x3 + qrow * LK;
  bf16x8 pb[8];

  #pragma unroll
  for (int half = 0; half < 2; ++half) {
    const int jt0 = half * 2, jt1 = half * 2 + 1;
    f32x16 s0 = zero16(), s1 = zero16();
    #pragma unroll
    for (int kt = 0; kt < 8; ++kt) {
      s0 = MFMA32(*(const bf16x8*)(sM + swz(jt0 * 32 + q31, kt * 32 + hi2 * 16)),
                  xbf[kt], s0);
      s1 = MFMA32(*(const bf16x8*)(sM + swz(jt1 * 32 + q31, kt * 32 + hi2 * 16)),
                  xbf[kt], s1);
    }

    #pragma unroll
    for (int jj = 0; jj < 2; ++jj) {
      f32x16& sj = jj ? s1 : s0;
      const int jt = half * 2 + jj;
      #pragma unroll
      for (int rg = 0; rg < 4; ++rg) {
        uint m0, m1, m2, m3;
        if (byteMode) {
          uint u = mu[jt * 4 + rg];
          m0 = u & 0xffu; m1 = (u >> 8) & 0xffu; m2 = (u >> 16) & 0xffu; m3 = u >> 24;
        } else {
          uint4 mw = *(const uint4*)(mrowW + jt * 32 + 8 * rg + 4 * hi2);
          m0 = mw.x; m1 = mw.y; m2 = mw.z; m3 = mw.w;
        }
        float p0 = __builtin_amdgcn_exp2f(sj[rg * 4 + 0] * C1);
        float p1 = __builtin_amdgcn_exp2f(sj[rg * 4 + 1] * C1);
        float p2 = __builtin_amdgcn_exp2f(sj[rg * 4 + 2] * C1);
        float p3 = __builtin_amdgcn_exp2f(sj[rg * 4 + 3] * C1);
        sj[rg * 4 + 0] = m0 ? 0.f : p0;
        sj[rg * 4 + 1] = m1 ? 0.f : p1;
        sj[rg * 4 + 2] = m2 ? 0.f : p2;
        sj[rg * 4 + 3] = m3 ? 0.f : p3;
      }

      // P^T B-frags in-register: cvt_pk pairs + permlane32_swap
      #pragma unroll
      for (int h = 0; h < 2; ++h) {
        uint A = pkbf(sj[h * 8 + 0], sj[h * 8 + 1]);
        uint C = pkbf(sj[h * 8 + 2], sj[h * 8 + 3]);
        uint B = pkbf(sj[h * 8 + 4], sj[h * 8 + 5]);
        uint D = pkbf(sj[h * 8 + 6], sj[h * 8 + 7]);
        asm("v_permlane32_swap_b32 %0, %1" : "+v"(A), "+v"(B));
        asm("v_permlane32_swap_b32 %0, %1" : "+v"(C), "+v"(D));
        uintx4 t; t.x = A; t.y = C; t.z = B; t.w = D;
        pb[jt * 2 + h] = __builtin_bit_cast(bf16x8, t);
      }
    }
  }

  // ---- dsum chain + first oc pair (3 independent MFMA chains) ----
  bf16x8 ones1;
  #pragma unroll
  for (int e = 0; e < 8; ++e) ones1[e] = (bf16_t)1.f;

  f32x16 dacc = zero16();
  {
    f32x16 o0 = zero16(), o1 = zero16();
    #pragma unroll
    for (int kt = 0; kt < 8; ++kt) {
      dacc = MFMA32(ones1, pb[kt], dacc);
      o0 = MFMA32(*(const bf16x8*)(sV + swz(0 * 32 + q31, kt * 32 + hi2 * 16)), pb[kt], o0);
      o1 = MFMA32(*(const bf16x8*)(sV + swz(1 * 32 + q31, kt * 32 + hi2 * 16)), pb[kt], o1);
    }
    const float inv = 1.0f / dacc[0];
    #pragma unroll
    for (int r = 0; r < 16; ++r) {
      const int ibase = (r & 3) + 8 * (r >> 2) + 4 * hi2;
      out[((size_t)b * LK + ibase) * LQ + q0w + q31] = o0[r] * inv;
      out[((size_t)b * LK + 32 + ibase) * LQ + q0w + q31] = o1[r] * inv;
    }
  }

  // ---- second oc pair ----
  {
    const float inv = 1.0f / dacc[0];
    f32x16 o2 = zero16(), o3 = zero16();
    #pragma unroll
    for (int kt = 0; kt < 8; ++kt) {
      o2 = MFMA32(*(const bf16x8*)(sV + swz(2 * 32 + q31, kt * 32 + hi2 * 16)), pb[kt], o2);
      o3 = MFMA32(*(const bf16x8*)(sV + swz(3 * 32 + q31, kt * 32 + hi2 * 16)), pb[kt], o3);
    }
    #pragma unroll
    for (int r = 0; r < 16; ++r) {
      const int ibase = (r & 3) + 8 * (r >> 2) + 4 * hi2;
      out[((size_t)b * LK + 64 + ibase) * LQ + q0w + q31] = o2[r] * inv;
      out[((size_t)b * LK + 96 + ibase) * LQ + q0w + q31] = o3[r] * inv;
    }
  }
}

extern "C" void kernel_launch(void* const* d_in, const int* in_sizes, int n_in,
                              void* d_out, int out_size, void* d_ws, size_t ws_size,
                              hipStream_t stream) {
  const float* x1 = (const float*)d_in[0];
  const float* x2 = (const float*)d_in[1];
  const void*  x3 = d_in[2];
  const float* wq = (const float*)d_in[3];
  const float* wk = (const float*)d_in[4];
  const float* wv = (const float*)d_in[5];
  uint8_t* ws = (uint8_t*)d_ws;
  float* out = (float*)d_out;

  prep_kernel<<<2 * NB, 512, 0, stream>>>(x2, wq, wk, wv, (const unsigned*)x3, ws);
  attn_kernel<<<NB * (LQ / 256), 512, 0, stream>>>(x1, x3, ws, out);
}

// Round 9
// 49.503 us; speedup vs baseline: 1.9241x; 1.0049x over previous
//
#include <hip/hip_runtime.h>
#include <hip/hip_bf16.h>
#include <stdint.h>

typedef __bf16 bf16_t;
typedef __bf16 bf16x8 __attribute__((ext_vector_type(8)));
typedef float  f32x4  __attribute__((ext_vector_type(4)));
typedef float  f32x16 __attribute__((ext_vector_type(16)));
typedef unsigned int uint;
typedef uint uintx4 __attribute__((ext_vector_type(4)));

#define MFMA16(a,b,c) __builtin_amdgcn_mfma_f32_16x16x32_bf16((a),(b),(c),0,0,0)
#define MFMA32(a,b,c) __builtin_amdgcn_mfma_f32_32x32x16_bf16((a),(b),(c),0,0,0)

constexpr int NB = 16;
constexpr int LQ = 8192;
constexpr int LK = 128;
constexpr int H  = 128;

// log2(e) / sqrt(H): fold softmax scale + exp2 conversion into one multiply
constexpr float C1 = 1.4426950408889634f / 11.313708498984761f;

constexpr size_t WS_FLAG = 0;
constexpr size_t WS_MV   = 1024;   // per batch: [M 32K | V 32K] swizzled bf16 LDS images

// XOR swizzle for [*][128] bf16 LDS tiles (row stride 256 B)
__device__ __forceinline__ unsigned swz(unsigned row, unsigned byte) {
  return row * 256u + (byte ^ ((row & 15u) << 4));
}

__device__ __forceinline__ bf16x8 cvt_frag(const float* p) {
  f32x4 u0 = *(const f32x4*)p;
  f32x4 u1 = *(const f32x4*)(p + 4);
  bf16x8 v;
  #pragma unroll
  for (int e = 0; e < 4; ++e) { v[e] = (bf16_t)u0[e]; v[e + 4] = (bf16_t)u1[e]; }
  return v;
}

__device__ __forceinline__ f32x16 zero16() {
  f32x16 z;
  #pragma unroll
  for (int i = 0; i < 16; ++i) z[i] = 0.f;
  return z;
}

// v_cvt_pk_bf16_f32: lo = bf16(a), hi = bf16(b)
__device__ __forceinline__ uint pkbf(float a, float b) {
  uint d;
  asm("v_cvt_pk_bf16_f32 %0, %1, %2" : "=v"(d) : "v"(a), "v"(b));
  return d;
}

// async global->LDS, 16 bytes per lane (dest must be wave-uniform base + lane*16)
__device__ __forceinline__ void gl16(const void* g, void* l) {
  __builtin_amdgcn_global_load_lds(
      (const __attribute__((address_space(1))) uint32_t*)g,
      (__attribute__((address_space(3))) uint32_t*)l, 16, 0, 0);
}

// ---------------------------------------------------------------------------
// prep (32 blocks): block 2b   -> M_b = x2_b @ (wq^T wk)  (swizzled image to ws)
//                   block 2b+1 -> V_b = x2_b @ wv^T       (swizzled image to ws)
// Block 0 also runs the mask-dtype probe. (unchanged from r8, validated)
// ---------------------------------------------------------------------------
__global__ __launch_bounds__(512) void prep_kernel(
    const float* __restrict__ x2, const float* __restrict__ wq,
    const float* __restrict__ wk, const float* __restrict__ wv,
    const unsigned* __restrict__ x3w, uint8_t* __restrict__ ws)
{
  __shared__ uint8_t sP[131072];  // [wqT 32K | wkT 32K | W2T lin 32K | out 32K]
  __shared__ int sF32, sBig;
  const int tid = threadIdx.x;
  const int b = blockIdx.x >> 1, which = blockIdx.x & 1;
  const int l = tid & 63, w = tid >> 6, q31 = l & 31, hi2 = l >> 5;
  uint8_t* sOut = sP + 98304;

  if (which == 0) {
    if (blockIdx.x == 0) {
      // mask dtype probe over first 2048 words of x3:
      // int32 bool -> words in {0,1}; uint8 bool -> words like 0x01010101 (>1);
      // f32 bool -> words in {0, 0x3f800000}
      if (tid == 0) { sF32 = 0; sBig = 0; }
      __syncthreads();
      int f = 0, g = 0;
      #pragma unroll
      for (int j = 0; j < 4; ++j) {
        unsigned v = x3w[tid * 4 + j];
        if (v == 0x3f800000u) f = 1;
        else if (v > 1u) g = 1;
      }
      if (f) sF32 = 1;
      if (g) sBig = 1;
      __syncthreads();
      if (tid == 0) *(int*)(ws + WS_FLAG) = (sF32 == 0 && sBig == 1) ? 1 : 0;
    }

    // stage wqT / wkT swizzled
    {
      const int row = tid >> 2, c0 = (tid & 3) * 32;
      #pragma unroll
      for (int wh = 0; wh < 2; ++wh) {
        const float* W = wh ? wk : wq;
        uint8_t* dst = sP + wh * 32768;
        const float* s = W + row * H + c0;
        #pragma unroll
        for (int j = 0; j < 32; ++j)
          *(bf16_t*)(dst + swz(c0 + j, row * 2)) = (bf16_t)s[j];
      }
    }
    __syncthreads();

    // W2T[i][j] = sum_k wq[k][i] wk[k][j]  -> LDS linear [128][128] bf16
    {
      const int lo = l & 15, hi = l >> 4;
      bf16x8 a4[4];
      #pragma unroll
      for (int kk = 0; kk < 4; ++kk)
        a4[kk] = *(const bf16x8*)(sP + swz(16 * w + lo, kk * 64 + hi * 16));
      bf16_t* W2T = (bf16_t*)(sP + 65536);
      #pragma unroll
      for (int t = 0; t < 8; ++t) {
        f32x4 c = {0.f, 0.f, 0.f, 0.f};
        #pragma unroll
        for (int kk = 0; kk < 4; ++kk)
          c = MFMA16(a4[kk], *(const bf16x8*)(sP + 32768 + swz(16 * t + lo, kk * 64 + hi * 16)), c);
        #pragma unroll
        for (int r = 0; r < 4; ++r)
          W2T[(16 * w + hi * 4 + r) * H + 16 * t + lo] = (bf16_t)c[r];
      }
    }
    __syncthreads();

    // M build
    if (w < 4) {
      const int wb = w;
      bf16x8 axf[8];
      const float* x2r = x2 + ((size_t)b * LK + 32 * wb + q31) * H;
      #pragma unroll
      for (int kt = 0; kt < 8; ++kt)
        axf[kt] = cvt_frag(x2r + kt * 16 + 8 * hi2);
      const bf16_t* W2Tl = (const bf16_t*)(sP + 65536);
      #pragma unroll
      for (int nt = 0; nt < 4; ++nt) {
        f32x16 c = zero16();
        #pragma unroll
        for (int kt = 0; kt < 8; ++kt)
          c = MFMA32(axf[kt],
                     *(const bf16x8*)(W2Tl + (size_t)(nt * 32 + q31) * H + kt * 16 + 8 * hi2), c);
        #pragma unroll
        for (int r = 0; r < 16; ++r)
          *(bf16_t*)(sOut + swz(32 * wb + (r & 3) + 8 * (r >> 2) + 4 * hi2,
                                (nt * 32 + q31) * 2)) = (bf16_t)c[r];
      }
    }
  } else {
    // V build
    if (w < 4) {
      const int wb = w;
      bf16x8 axf[8];
      const float* x2r = x2 + ((size_t)b * LK + 32 * wb + q31) * H;
      #pragma unroll
      for (int kt = 0; kt < 8; ++kt)
        axf[kt] = cvt_frag(x2r + kt * 16 + 8 * hi2);
      #pragma unroll
      for (int nt = 0; nt < 4; ++nt) {
        f32x16 c = zero16();
        #pragma unroll
        for (int kt = 0; kt < 8; ++kt)
          c = MFMA32(axf[kt],
                     cvt_frag(wv + (size_t)(nt * 32 + q31) * H + kt * 16 + 8 * hi2), c);
        #pragma unroll
        for (int r = 0; r < 16; ++r)
          *(bf16_t*)(sOut + swz(32 * wb + (r & 3) + 8 * (r >> 2) + 4 * hi2,
                                (nt * 32 + q31) * 2)) = (bf16_t)c[r];
      }
    }
  }
  __syncthreads();

  // copy the 32 KB swizzled image to ws (linear)
  {
    const uint4* src = (const uint4*)sOut;
    uint4* dst = (uint4*)(ws + WS_MV + (size_t)b * 65536 + (size_t)which * 32768);
    #pragma unroll
    for (int j = 0; j < 4; ++j)
      dst[tid + j * 512] = src[tid + j * 512];
  }
}

// ---------------------------------------------------------------------------
// Main fused kernel. Grid 512 (16 b x 32 chunks of 256 q rows); 8 waves;
// one 32-row subtile per wave; __launch_bounds__(512,4) -> VGPR<=128,
// 2 blocks/CU = 16 waves/CU.
// Concurrency recipe: (1) M/V image streamed via global_load_lds (no VGPR
// cost, 8 issues/thread in flight), (2) x1 batched as 16 raw dwordx4 loads
// per lane (64 VGPRs of loads in flight), converted after the barrier,
// (3) s_setprio(1) around MFMA clusters.
// ---------------------------------------------------------------------------
__global__ __launch_bounds__(512, 4) void attn_kernel(
    const float* __restrict__ x1, const void* __restrict__ x3,
    const uint8_t* __restrict__ ws, float* __restrict__ out)
{
  __shared__ uint8_t sm[65536];
  uint8_t* sM = sm;            // M [128 j][128 c] bf16 swizzled
  uint8_t* sV = sm + 32768;    // V [128 i][128 j] bf16 swizzled

  const int tid = threadIdx.x, blk = blockIdx.x;
  const int b = blk >> 5, qc = (blk & 31) * 256;
  const int l = tid & 63, w = tid >> 6;
  const int q31 = l & 31, hi2 = l >> 5;
  const int byteMode = *(const int*)(ws + WS_FLAG);

  const int q0w = qc + w * 32;
  const size_t qrow = (size_t)b * LQ + q0w + q31;   // this lane's q row

  // ---- M/V image: async global->LDS (64 KB, L2-resident after first use) ----
  {
    const uint8_t* g = ws + WS_MV + (size_t)b * 65536;
    #pragma unroll
    for (int j = 0; j < 8; ++j)
      gl16(g + tid * 16 + j * 8192, sm + tid * 16 + j * 8192);
  }

  // ---- x1: 16 raw dwordx4 loads per lane, all in flight ----
  f32x4 xr[16];
  {
    const float* xp = x1 + qrow * H;
    #pragma unroll
    for (int kt = 0; kt < 8; ++kt) {
      xr[2 * kt]     = *(const f32x4*)(xp + kt * 16 + 8 * hi2);
      xr[2 * kt + 1] = *(const f32x4*)(xp + kt * 16 + 8 * hi2 + 4);
    }
  }

  // ---- mask prefetch (byte mode) ----
  uint mu[16];
  if (byteMode) {
    const uint8_t* mp = (const uint8_t*)x3 + qrow * LK;
    #pragma unroll
    for (int jt = 0; jt < 4; ++jt)
      #pragma unroll
      for (int rg = 0; rg < 4; ++rg)
        mu[jt * 4 + rg] = *(const uint*)(mp + jt * 32 + 8 * rg + 4 * hi2);
  }
  __syncthreads();   // drains gload_lds + x1 + mask

  // convert x1 to bf16 B-frags
  bf16x8 xbf[8];
  #pragma unroll
  for (int kt = 0; kt < 8; ++kt)
    #pragma unroll
    for (int e = 0; e < 4; ++e) {
      xbf[kt][e]     = (bf16_t)xr[2 * kt][e];
      xbf[kt][e + 4] = (bf16_t)xr[2 * kt + 1][e];
    }

  // ---- S^T = M @ x1^T in two j-tile pairs; pack to bf16 pb-frags ----
  const uint* mrowW = (const uint*)x3 + qrow * LK;
  bf16x8 pb[8];

  #pragma unroll
  for (int half = 0; half < 2; ++half) {
    const int jt0 = half * 2, jt1 = half * 2 + 1;
    f32x16 s0 = zero16(), s1 = zero16();
    __builtin_amdgcn_s_setprio(1);
    #pragma unroll
    for (int kt = 0; kt < 8; ++kt) {
      s0 = MFMA32(*(const bf16x8*)(sM + swz(jt0 * 32 + q31, kt * 32 + hi2 * 16)),
                  xbf[kt], s0);
      s1 = MFMA32(*(const bf16x8*)(sM + swz(jt1 * 32 + q31, kt * 32 + hi2 * 16)),
                  xbf[kt], s1);
    }
    __builtin_amdgcn_s_setprio(0);

    #pragma unroll
    for (int jj = 0; jj < 2; ++jj) {
      f32x16& sj = jj ? s1 : s0;
      const int jt = half * 2 + jj;
      #pragma unroll
      for (int rg = 0; rg < 4; ++rg) {
        uint m0, m1, m2, m3;
        if (byteMode) {
          uint u = mu[jt * 4 + rg];
          m0 = u & 0xffu; m1 = (u >> 8) & 0xffu; m2 = (u >> 16) & 0xffu; m3 = u >> 24;
        } else {
          uint4 mw = *(const uint4*)(mrowW + jt * 32 + 8 * rg + 4 * hi2);
          m0 = mw.x; m1 = mw.y; m2 = mw.z; m3 = mw.w;
        }
        float p0 = __builtin_amdgcn_exp2f(sj[rg * 4 + 0] * C1);
        float p1 = __builtin_amdgcn_exp2f(sj[rg * 4 + 1] * C1);
        float p2 = __builtin_amdgcn_exp2f(sj[rg * 4 + 2] * C1);
        float p3 = __builtin_amdgcn_exp2f(sj[rg * 4 + 3] * C1);
        sj[rg * 4 + 0] = m0 ? 0.f : p0;
        sj[rg * 4 + 1] = m1 ? 0.f : p1;
        sj[rg * 4 + 2] = m2 ? 0.f : p2;
        sj[rg * 4 + 3] = m3 ? 0.f : p3;
      }

      // P^T B-frags in-register: cvt_pk pairs + permlane32_swap
      #pragma unroll
      for (int h = 0; h < 2; ++h) {
        uint A = pkbf(sj[h * 8 + 0], sj[h * 8 + 1]);
        uint C = pkbf(sj[h * 8 + 2], sj[h * 8 + 3]);
        uint B = pkbf(sj[h * 8 + 4], sj[h * 8 + 5]);
        uint D = pkbf(sj[h * 8 + 6], sj[h * 8 + 7]);
        asm("v_permlane32_swap_b32 %0, %1" : "+v"(A), "+v"(B));
        asm("v_permlane32_swap_b32 %0, %1" : "+v"(C), "+v"(D));
        uintx4 t; t.x = A; t.y = C; t.z = B; t.w = D;
        pb[jt * 2 + h] = __builtin_bit_cast(bf16x8, t);
      }
    }
  }

  // ---- dsum chain + first oc pair (3 independent MFMA chains) ----
  bf16x8 ones1;
  #pragma unroll
  for (int e = 0; e < 8; ++e) ones1[e] = (bf16_t)1.f;

  f32x16 dacc = zero16();
  {
    f32x16 o0 = zero16(), o1 = zero16();
    __builtin_amdgcn_s_setprio(1);
    #pragma unroll
    for (int kt = 0; kt < 8; ++kt) {
      dacc = MFMA32(ones1, pb[kt], dacc);
      o0 = MFMA32(*(const bf16x8*)(sV + swz(0 * 32 + q31, kt * 32 + hi2 * 16)), pb[kt], o0);
      o1 = MFMA32(*(const bf16x8*)(sV + swz(1 * 32 + q31, kt * 32 + hi2 * 16)), pb[kt], o1);
    }
    __builtin_amdgcn_s_setprio(0);
    const float inv = 1.0f / dacc[0];
    #pragma unroll
    for (int r = 0; r < 16; ++r) {
      const int ibase = (r & 3) + 8 * (r >> 2) + 4 * hi2;
      out[((size_t)b * LK + ibase) * LQ + q0w + q31] = o0[r] * inv;
      out[((size_t)b * LK + 32 + ibase) * LQ + q0w + q31] = o1[r] * inv;
    }
  }

  // ---- second oc pair ----
  {
    const float inv = 1.0f / dacc[0];
    f32x16 o2 = zero16(), o3 = zero16();
    __builtin_amdgcn_s_setprio(1);
    #pragma unroll
    for (int kt = 0; kt < 8; ++kt) {
      o2 = MFMA32(*(const bf16x8*)(sV + swz(2 * 32 + q31, kt * 32 + hi2 * 16)), pb[kt], o2);
      o3 = MFMA32(*(const bf16x8*)(sV + swz(3 * 32 + q31, kt * 32 + hi2 * 16)), pb[kt], o3);
    }
    __builtin_amdgcn_s_setprio(0);
    #pragma unroll
    for (int r = 0; r < 16; ++r) {
      const int ibase = (r & 3) + 8 * (r >> 2) + 4 * hi2;
      out[((size_t)b * LK + 64 + ibase) * LQ + q0w + q31] = o2[r] * inv;
      out[((size_t)b * LK + 96 + ibase) * LQ + q0w + q31] = o3[r] * inv;
    }
  }
}

extern "C" void kernel_launch(void* const* d_in, const int* in_sizes, int n_in,
                              void* d_out, int out_size, void* d_ws, size_t ws_size,
                              hipStream_t stream) {
  const float* x1 = (const float*)d_in[0];
  const float* x2 = (const float*)d_in[1];
  const void*  x3 = d_in[2];
  const float* wq = (const float*)d_in[3];
  const float* wk = (const float*)d_in[4];
  const float* wv = (const float*)d_in[5];
  uint8_t* ws = (uint8_t*)d_ws;
  float* out = (float*)d_out;

  prep_kernel<<<2 * NB, 512, 0, stream>>>(x2, wq, wk, wv, (const unsigned*)x3, ws);
  attn_kernel<<<NB * (LQ / 256), 512, 0, stream>>>(x1, x3, ws, out);
}

// Round 10
// 49.312 us; speedup vs baseline: 1.9316x; 1.0039x over previous
//
#include <hip/hip_runtime.h>
#include <hip/hip_bf16.h>
#include <stdint.h>

typedef __bf16 bf16_t;
typedef __bf16 bf16x8 __attribute__((ext_vector_type(8)));
typedef float  f32x4  __attribute__((ext_vector_type(4)));
typedef float  f32x16 __attribute__((ext_vector_type(16)));
typedef unsigned int uint;
typedef uint uintx4 __attribute__((ext_vector_type(4)));

#define MFMA16(a,b,c) __builtin_amdgcn_mfma_f32_16x16x32_bf16((a),(b),(c),0,0,0)
#define MFMA32(a,b,c) __builtin_amdgcn_mfma_f32_32x32x16_bf16((a),(b),(c),0,0,0)

constexpr int NB = 16;
constexpr int LQ = 8192;
constexpr int LK = 128;
constexpr int H  = 128;

// log2(e) / sqrt(H): fold softmax scale + exp2 conversion into one multiply
constexpr float C1 = 1.4426950408889634f / 11.313708498984761f;

constexpr size_t WS_FLAG = 0;
constexpr size_t WS_MV   = 1024;   // per batch: [M 32K | V 32K] swizzled bf16 LDS images

// XOR swizzle for [*][128] bf16 LDS tiles (row stride 256 B)
__device__ __forceinline__ unsigned swz(unsigned row, unsigned byte) {
  return row * 256u + (byte ^ ((row & 15u) << 4));
}

__device__ __forceinline__ bf16x8 cvt_frag(const float* p) {
  f32x4 u0 = *(const f32x4*)p;
  f32x4 u1 = *(const f32x4*)(p + 4);
  bf16x8 v;
  #pragma unroll
  for (int e = 0; e < 4; ++e) { v[e] = (bf16_t)u0[e]; v[e + 4] = (bf16_t)u1[e]; }
  return v;
}

__device__ __forceinline__ f32x16 zero16() {
  f32x16 z;
  #pragma unroll
  for (int i = 0; i < 16; ++i) z[i] = 0.f;
  return z;
}

// v_cvt_pk_bf16_f32: lo = bf16(a), hi = bf16(b)
__device__ __forceinline__ uint pkbf(float a, float b) {
  uint d;
  asm("v_cvt_pk_bf16_f32 %0, %1, %2" : "=v"(d) : "v"(a), "v"(b));
  return d;
}

// async global->LDS, 16 bytes per lane (dest must be wave-uniform base + lane*16)
__device__ __forceinline__ void gl16(const void* g, void* l) {
  __builtin_amdgcn_global_load_lds(
      (const __attribute__((address_space(1))) uint32_t*)g,
      (__attribute__((address_space(3))) uint32_t*)l, 16, 0, 0);
}

// ---------------------------------------------------------------------------
// prep (32 blocks): block 2b   -> M_b = x2_b @ (wq^T wk)  (swizzled image to ws)
//                   block 2b+1 -> V_b = x2_b @ wv^T       (swizzled image to ws)
// Block 0 also runs the mask-dtype probe. (unchanged from r8/r9, validated)
// ---------------------------------------------------------------------------
__global__ __launch_bounds__(512) void prep_kernel(
    const float* __restrict__ x2, const float* __restrict__ wq,
    const float* __restrict__ wk, const float* __restrict__ wv,
    const unsigned* __restrict__ x3w, uint8_t* __restrict__ ws)
{
  __shared__ uint8_t sP[131072];  // [wqT 32K | wkT 32K | W2T lin 32K | out 32K]
  __shared__ int sF32, sBig;
  const int tid = threadIdx.x;
  const int b = blockIdx.x >> 1, which = blockIdx.x & 1;
  const int l = tid & 63, w = tid >> 6, q31 = l & 31, hi2 = l >> 5;
  uint8_t* sOut = sP + 98304;

  if (which == 0) {
    if (blockIdx.x == 0) {
      // mask dtype probe over first 2048 words of x3:
      // int32 bool -> words in {0,1}; uint8 bool -> words like 0x01010101 (>1);
      // f32 bool -> words in {0, 0x3f800000}
      if (tid == 0) { sF32 = 0; sBig = 0; }
      __syncthreads();
      int f = 0, g = 0;
      #pragma unroll
      for (int j = 0; j < 4; ++j) {
        unsigned v = x3w[tid * 4 + j];
        if (v == 0x3f800000u) f = 1;
        else if (v > 1u) g = 1;
      }
      if (f) sF32 = 1;
      if (g) sBig = 1;
      __syncthreads();
      if (tid == 0) *(int*)(ws + WS_FLAG) = (sF32 == 0 && sBig == 1) ? 1 : 0;
    }

    // stage wqT / wkT swizzled
    {
      const int row = tid >> 2, c0 = (tid & 3) * 32;
      #pragma unroll
      for (int wh = 0; wh < 2; ++wh) {
        const float* W = wh ? wk : wq;
        uint8_t* dst = sP + wh * 32768;
        const float* s = W + row * H + c0;
        #pragma unroll
        for (int j = 0; j < 32; ++j)
          *(bf16_t*)(dst + swz(c0 + j, row * 2)) = (bf16_t)s[j];
      }
    }
    __syncthreads();

    // W2T[i][j] = sum_k wq[k][i] wk[k][j]  -> LDS linear [128][128] bf16
    {
      const int lo = l & 15, hi = l >> 4;
      bf16x8 a4[4];
      #pragma unroll
      for (int kk = 0; kk < 4; ++kk)
        a4[kk] = *(const bf16x8*)(sP + swz(16 * w + lo, kk * 64 + hi * 16));
      bf16_t* W2T = (bf16_t*)(sP + 65536);
      #pragma unroll
      for (int t = 0; t < 8; ++t) {
        f32x4 c = {0.f, 0.f, 0.f, 0.f};
        #pragma unroll
        for (int kk = 0; kk < 4; ++kk)
          c = MFMA16(a4[kk], *(const bf16x8*)(sP + 32768 + swz(16 * t + lo, kk * 64 + hi * 16)), c);
        #pragma unroll
        for (int r = 0; r < 4; ++r)
          W2T[(16 * w + hi * 4 + r) * H + 16 * t + lo] = (bf16_t)c[r];
      }
    }
    __syncthreads();

    // M build
    if (w < 4) {
      const int wb = w;
      bf16x8 axf[8];
      const float* x2r = x2 + ((size_t)b * LK + 32 * wb + q31) * H;
      #pragma unroll
      for (int kt = 0; kt < 8; ++kt)
        axf[kt] = cvt_frag(x2r + kt * 16 + 8 * hi2);
      const bf16_t* W2Tl = (const bf16_t*)(sP + 65536);
      #pragma unroll
      for (int nt = 0; nt < 4; ++nt) {
        f32x16 c = zero16();
        #pragma unroll
        for (int kt = 0; kt < 8; ++kt)
          c = MFMA32(axf[kt],
                     *(const bf16x8*)(W2Tl + (size_t)(nt * 32 + q31) * H + kt * 16 + 8 * hi2), c);
        #pragma unroll
        for (int r = 0; r < 16; ++r)
          *(bf16_t*)(sOut + swz(32 * wb + (r & 3) + 8 * (r >> 2) + 4 * hi2,
                                (nt * 32 + q31) * 2)) = (bf16_t)c[r];
      }
    }
  } else {
    // V build
    if (w < 4) {
      const int wb = w;
      bf16x8 axf[8];
      const float* x2r = x2 + ((size_t)b * LK + 32 * wb + q31) * H;
      #pragma unroll
      for (int kt = 0; kt < 8; ++kt)
        axf[kt] = cvt_frag(x2r + kt * 16 + 8 * hi2);
      #pragma unroll
      for (int nt = 0; nt < 4; ++nt) {
        f32x16 c = zero16();
        #pragma unroll
        for (int kt = 0; kt < 8; ++kt)
          c = MFMA32(axf[kt],
                     cvt_frag(wv + (size_t)(nt * 32 + q31) * H + kt * 16 + 8 * hi2), c);
        #pragma unroll
        for (int r = 0; r < 16; ++r)
          *(bf16_t*)(sOut + swz(32 * wb + (r & 3) + 8 * (r >> 2) + 4 * hi2,
                                (nt * 32 + q31) * 2)) = (bf16_t)c[r];
      }
    }
  }
  __syncthreads();

  // copy the 32 KB swizzled image to ws (linear)
  {
    const uint4* src = (const uint4*)sOut;
    uint4* dst = (uint4*)(ws + WS_MV + (size_t)b * 65536 + (size_t)which * 32768);
    #pragma unroll
    for (int j = 0; j < 4; ++j)
      dst[tid + j * 512] = src[tid + j * 512];
  }
}

// ---------------------------------------------------------------------------
// Main fused kernel. Grid 512 (16 b x 32 chunks of 256 q rows); 8 waves;
// one 32-row subtile per wave; LDS 64 KB -> 2 blocks/CU = 16 waves/CU.
// amdgpu_waves_per_eu(4,4) pins the allocator to the 128-VGPR budget so the
// 16 raw x1 dwordx4 loads stay live in flight (r9's VGPR=64 serialized them).
// sched_barrier(0) after the issue block prevents load sinking.
// ---------------------------------------------------------------------------
__global__ __attribute__((amdgpu_flat_work_group_size(512, 512),
                          amdgpu_waves_per_eu(4, 4)))
void attn_kernel(
    const float* __restrict__ x1, const void* __restrict__ x3,
    const uint8_t* __restrict__ ws, float* __restrict__ out)
{
  __shared__ uint8_t sm[65536];
  uint8_t* sM = sm;            // M [128 j][128 c] bf16 swizzled
  uint8_t* sV = sm + 32768;    // V [128 i][128 j] bf16 swizzled

  const int tid = threadIdx.x, blk = blockIdx.x;
  const int b = blk >> 5, qc = (blk & 31) * 256;
  const int l = tid & 63, w = tid >> 6;
  const int q31 = l & 31, hi2 = l >> 5;
  const int byteMode = *(const int*)(ws + WS_FLAG);

  const int q0w = qc + w * 32;
  const size_t qrow = (size_t)b * LQ + q0w + q31;   // this lane's q row

  // ---- M/V image: async global->LDS (64 KB, L2-resident after first use) ----
  {
    const uint8_t* g = ws + WS_MV + (size_t)b * 65536;
    #pragma unroll
    for (int j = 0; j < 8; ++j)
      gl16(g + tid * 16 + j * 8192, sm + tid * 16 + j * 8192);
  }

  // ---- x1: 16 raw dwordx4 loads per lane, all in flight ----
  f32x4 xr[16];
  {
    const float* xp = x1 + qrow * H;
    #pragma unroll
    for (int kt = 0; kt < 8; ++kt) {
      xr[2 * kt]     = *(const f32x4*)(xp + kt * 16 + 8 * hi2);
      xr[2 * kt + 1] = *(const f32x4*)(xp + kt * 16 + 8 * hi2 + 4);
    }
  }

  // ---- mask prefetch (byte mode) ----
  uint mu[16];
  if (byteMode) {
    const uint8_t* mp = (const uint8_t*)x3 + qrow * LK;
    #pragma unroll
    for (int jt = 0; jt < 4; ++jt)
      #pragma unroll
      for (int rg = 0; rg < 4; ++rg)
        mu[jt * 4 + rg] = *(const uint*)(mp + jt * 32 + 8 * rg + 4 * hi2);
  }
  __builtin_amdgcn_sched_barrier(0);   // pin: all loads issued before anything else
  __syncthreads();   // drains gload_lds + x1 + mask

  // convert x1 to bf16 B-frags
  bf16x8 xbf[8];
  #pragma unroll
  for (int kt = 0; kt < 8; ++kt)
    #pragma unroll
    for (int e = 0; e < 4; ++e) {
      xbf[kt][e]     = (bf16_t)xr[2 * kt][e];
      xbf[kt][e + 4] = (bf16_t)xr[2 * kt + 1][e];
    }

  // ---- S^T = M @ x1^T in two j-tile pairs; pack to bf16 pb-frags ----
  const uint* mrowW = (const uint*)x3 + qrow * LK;
  bf16x8 pb[8];

  #pragma unroll
  for (int half = 0; half < 2; ++half) {
    const int jt0 = half * 2, jt1 = half * 2 + 1;
    f32x16 s0 = zero16(), s1 = zero16();
    __builtin_amdgcn_s_setprio(1);
    #pragma unroll
    for (int kt = 0; kt < 8; ++kt) {
      s0 = MFMA32(*(const bf16x8*)(sM + swz(jt0 * 32 + q31, kt * 32 + hi2 * 16)),
                  xbf[kt], s0);
      s1 = MFMA32(*(const bf16x8*)(sM + swz(jt1 * 32 + q31, kt * 32 + hi2 * 16)),
                  xbf[kt], s1);
    }
    __builtin_amdgcn_s_setprio(0);

    #pragma unroll
    for (int jj = 0; jj < 2; ++jj) {
      f32x16& sj = jj ? s1 : s0;
      const int jt = half * 2 + jj;
      #pragma unroll
      for (int rg = 0; rg < 4; ++rg) {
        uint m0, m1, m2, m3;
        if (byteMode) {
          uint u = mu[jt * 4 + rg];
          m0 = u & 0xffu; m1 = (u >> 8) & 0xffu; m2 = (u >> 16) & 0xffu; m3 = u >> 24;
        } else {
          uint4 mw = *(const uint4*)(mrowW + jt * 32 + 8 * rg + 4 * hi2);
          m0 = mw.x; m1 = mw.y; m2 = mw.z; m3 = mw.w;
        }
        float p0 = __builtin_amdgcn_exp2f(sj[rg * 4 + 0] * C1);
        float p1 = __builtin_amdgcn_exp2f(sj[rg * 4 + 1] * C1);
        float p2 = __builtin_amdgcn_exp2f(sj[rg * 4 + 2] * C1);
        float p3 = __builtin_amdgcn_exp2f(sj[rg * 4 + 3] * C1);
        sj[rg * 4 + 0] = m0 ? 0.f : p0;
        sj[rg * 4 + 1] = m1 ? 0.f : p1;
        sj[rg * 4 + 2] = m2 ? 0.f : p2;
        sj[rg * 4 + 3] = m3 ? 0.f : p3;
      }

      // P^T B-frags in-register: cvt_pk pairs + permlane32_swap
      #pragma unroll
      for (int h = 0; h < 2; ++h) {
        uint A = pkbf(sj[h * 8 + 0], sj[h * 8 + 1]);
        uint C = pkbf(sj[h * 8 + 2], sj[h * 8 + 3]);
        uint B = pkbf(sj[h * 8 + 4], sj[h * 8 + 5]);
        uint D = pkbf(sj[h * 8 + 6], sj[h * 8 + 7]);
        asm("v_permlane32_swap_b32 %0, %1" : "+v"(A), "+v"(B));
        asm("v_permlane32_swap_b32 %0, %1" : "+v"(C), "+v"(D));
        uintx4 t; t.x = A; t.y = C; t.z = B; t.w = D;
        pb[jt * 2 + h] = __builtin_bit_cast(bf16x8, t);
      }
    }
  }

  // ---- dsum chain + first oc pair (3 independent MFMA chains) ----
  bf16x8 ones1;
  #pragma unroll
  for (int e = 0; e < 8; ++e) ones1[e] = (bf16_t)1.f;

  f32x16 dacc = zero16();
  {
    f32x16 o0 = zero16(), o1 = zero16();
    __builtin_amdgcn_s_setprio(1);
    #pragma unroll
    for (int kt = 0; kt < 8; ++kt) {
      dacc = MFMA32(ones1, pb[kt], dacc);
      o0 = MFMA32(*(const bf16x8*)(sV + swz(0 * 32 + q31, kt * 32 + hi2 * 16)), pb[kt], o0);
      o1 = MFMA32(*(const bf16x8*)(sV + swz(1 * 32 + q31, kt * 32 + hi2 * 16)), pb[kt], o1);
    }
    __builtin_amdgcn_s_setprio(0);
    const float inv = 1.0f / dacc[0];
    #pragma unroll
    for (int r = 0; r < 16; ++r) {
      const int ibase = (r & 3) + 8 * (r >> 2) + 4 * hi2;
      out[((size_t)b * LK + ibase) * LQ + q0w + q31] = o0[r] * inv;
      out[((size_t)b * LK + 32 + ibase) * LQ + q0w + q31] = o1[r] * inv;
    }
  }

  // ---- second oc pair ----
  {
    const float inv = 1.0f / dacc[0];
    f32x16 o2 = zero16(), o3 = zero16();
    __builtin_amdgcn_s_setprio(1);
    #pragma unroll
    for (int kt = 0; kt < 8; ++kt) {
      o2 = MFMA32(*(const bf16x8*)(sV + swz(2 * 32 + q31, kt * 32 + hi2 * 16)), pb[kt], o2);
      o3 = MFMA32(*(const bf16x8*)(sV + swz(3 * 32 + q31, kt * 32 + hi2 * 16)), pb[kt], o3);
    }
    __builtin_amdgcn_s_setprio(0);
    #pragma unroll
    for (int r = 0; r < 16; ++r) {
      const int ibase = (r & 3) + 8 * (r >> 2) + 4 * hi2;
      out[((size_t)b * LK + 64 + ibase) * LQ + q0w + q31] = o2[r] * inv;
      out[((size_t)b * LK + 96 + ibase) * LQ + q0w + q31] = o3[r] * inv;
    }
  }
}

extern "C" void kernel_launch(void* const* d_in, const int* in_sizes, int n_in,
                              void* d_out, int out_size, void* d_ws, size_t ws_size,
                              hipStream_t stream) {
  const float* x1 = (const float*)d_in[0];
  const float* x2 = (const float*)d_in[1];
  const void*  x3 = d_in[2];
  const float* wq = (const float*)d_in[3];
  const float* wk = (const float*)d_in[4];
  const float* wv = (const float*)d_in[5];
  uint8_t* ws = (uint8_t*)d_ws;
  float* out = (float*)d_out;

  prep_kernel<<<2 * NB, 512, 0, stream>>>(x2, wq, wk, wv, (const unsigned*)x3, ws);
  attn_kernel<<<NB * (LQ / 256), 512, 0, stream>>>(x1, x3, ws, out);
}